// Round 1
// baseline (97217.041 us; speedup 1.0000x reference)
//
#include <hip/hip_runtime.h>

#define NN    500
#define TT    20000
#define NPAD  512
#define NBLK  8
#define NROW  64        // padded rows per block
#define TPB   512
#define RPT   4         // rows per thread
#define CPT   16        // cols per thread (strided by 32)
#define DTC   0.05f
#define SQDTC 0.22360679774997896f

// ---------------------------------------------------------------------------
// Workspace layout (d_ws): pub[2][NPAD] (ull = packed float2), then flags[NBLK]
// ---------------------------------------------------------------------------

__global__ __launch_bounds__(512) void hopf_init_ws(unsigned long long* pub, int* flags) {
    int i = blockIdx.x * blockDim.x + threadIdx.x;
    if (i < 2 * NPAD) pub[i] = 0ull;
    if (i < NBLK) flags[i] = 0;
}

__global__ __launch_bounds__(TPB) void hopf_main(
    const float* __restrict__ sc, const float* __restrict__ x0,
    const float* __restrict__ y0, const float* __restrict__ aa,
    const float* __restrict__ om, const float* __restrict__ noise,
    const float* __restrict__ gg, float* __restrict__ out,
    unsigned long long* __restrict__ pub, int* __restrict__ flags)
{
    const int tid  = threadIdx.x;
    const int blk  = blockIdx.x;
    const int cgrp = tid & 31;       // 32 column groups
    const int rgrp = tid >> 5;       // 16 row groups of RPT rows
    const int r0   = blk * NROW + rgrp * RPT;   // padded global row base

    __shared__ __align__(16) float2 xy[NPAD];   // full padded state (x,y)

    // ---- sc slice -> registers.  col(c) = cgrp + 32*c  (strided => LDS reads
    // of xy are lane-consecutive ds_read_b64, conflict-free) ----
    float scr[RPT][CPT];
#pragma unroll
    for (int r = 0; r < RPT; ++r) {
        int row = r0 + r;
#pragma unroll
        for (int c = 0; c < CPT; ++c) {
            int col = cgrp + 32 * c;
            scr[r][c] = (row < NN && col < NN) ? sc[row * NN + col] : 0.0f;
        }
    }

    // ---- deg per row: butterfly over the 32 lanes of the column groups ----
    float dsum[RPT];
#pragma unroll
    for (int r = 0; r < RPT; ++r) {
        float s = 0.f;
#pragma unroll
        for (int c = 0; c < CPT; ++c) s += scr[r][c];
        dsum[r] = s;
    }
#pragma unroll
    for (int m = 16; m >= 1; m >>= 1) {
#pragma unroll
        for (int r = 0; r < RPT; ++r) dsum[r] += __shfl_xor(dsum[r], m, 32);
    }

    // ---- per-finalize-lane constants (lanes cgrp<RPT own row r0+cgrp) ----
    float a_i = 0.f, om_i = 0.f, deg_i = 0.f;
    int myrow = -1;
    if (cgrp < RPT) {
        int row = r0 + cgrp;
        deg_i = (cgrp == 0) ? dsum[0] : (cgrp == 1) ? dsum[1]
              : (cgrp == 2) ? dsum[2] : dsum[3];
        if (row < NN) { myrow = row; a_i = aa[row]; om_i = om[row]; }
    }
    const float g = gg[0];

    // ---- initial state into LDS ----
    xy[tid] = (tid < NN) ? make_float2(x0[tid], y0[tid]) : make_float2(0.f, 0.f);
    __syncthreads();

    // prefetched noise for step 0
    float2 nz = make_float2(0.f, 0.f);
    if (myrow >= 0) nz = *(const float2*)(noise + 2 * (size_t)myrow);

    for (int t = 0; t < TT; ++t) {
        // prefetch next step's noise (hidden under the matvec)
        float2 nz_next = make_float2(0.f, 0.f);
        if (myrow >= 0 && t + 1 < TT)
            nz_next = *(const float2*)(noise + (size_t)(t + 1) * (2 * NN) + 2 * (size_t)myrow);

        // ---- partial matvec: 4 rows x 16 strided cols per thread ----
        float2 acc[RPT];
#pragma unroll
        for (int r = 0; r < RPT; ++r) acc[r] = make_float2(0.f, 0.f);
#pragma unroll
        for (int c = 0; c < CPT; ++c) {
            float2 w = xy[cgrp + 32 * c];
#pragma unroll
            for (int r = 0; r < RPT; ++r) {
                acc[r].x += scr[r][c] * w.x;
                acc[r].y += scr[r][c] * w.y;
            }
        }
        // ---- reduce across the 32 column-group lanes ----
#pragma unroll
        for (int m = 16; m >= 1; m >>= 1) {
#pragma unroll
            for (int r = 0; r < RPT; ++r) {
                acc[r].x += __shfl_xor(acc[r].x, m, 32);
                acc[r].y += __shfl_xor(acc[r].y, m, 32);
            }
        }

        // ---- finalize + publish (lanes cgrp<RPT, real rows only) ----
        if (myrow >= 0) {
            float sx = (cgrp == 0) ? acc[0].x : (cgrp == 1) ? acc[1].x
                     : (cgrp == 2) ? acc[2].x : acc[3].x;
            float sy = (cgrp == 0) ? acc[0].y : (cgrp == 1) ? acc[1].y
                     : (cgrp == 2) ? acc[2].y : acc[3].y;
            float2 cur = xy[myrow];
            float r2 = cur.x * cur.x + cur.y * cur.y;
            float cx = sx - deg_i * cur.x;
            float cy = sy - deg_i * cur.y;
            float dx = (a_i - r2) * cur.x - om_i * cur.y + g * cx;
            float dy = (a_i - r2) * cur.y + om_i * cur.x + g * cy;
            float xn = cur.x + DTC * dx + SQDTC * nz.x;
            float yn = cur.y + DTC * dy + SQDTC * nz.y;
            out[(size_t)t * NN + myrow] = xn;
            float2 p = make_float2(xn, yn);
            unsigned long long pv;
            __builtin_memcpy(&pv, &p, 8);
            __hip_atomic_store(&pub[(size_t)(t & 1) * NPAD + myrow], pv,
                               __ATOMIC_RELAXED, __HIP_MEMORY_SCOPE_AGENT);
        }
        nz = nz_next;

        if (t == TT - 1) break;   // uniform across grid

        // ---- publish fence -> flag ----
        __threadfence();          // agent-scope: pub stores reach coherence point
        __syncthreads();
        if (tid == 0)
            __hip_atomic_store(&flags[blk], t + 1,
                               __ATOMIC_RELEASE, __HIP_MEMORY_SCOPE_AGENT);

        // ---- wait for all producers of step t ----
        if (tid < NBLK && tid != blk) {
            while (__hip_atomic_load(&flags[tid], __ATOMIC_ACQUIRE,
                                     __HIP_MEMORY_SCOPE_AGENT) < t + 1) { }
        }
        __syncthreads();

        // ---- gather full state t+1: one 8B coherent load per thread ----
        unsigned long long pv = __hip_atomic_load(&pub[(size_t)(t & 1) * NPAD + tid],
                                                  __ATOMIC_RELAXED, __HIP_MEMORY_SCOPE_AGENT);
        float2 w;
        __builtin_memcpy(&w, &pv, 8);
        xy[tid] = w;
        __syncthreads();
    }
}

extern "C" void kernel_launch(void* const* d_in, const int* in_sizes, int n_in,
                              void* d_out, int out_size, void* d_ws, size_t ws_size,
                              hipStream_t stream) {
    const float* sc = (const float*)d_in[0];
    const float* x0 = (const float*)d_in[1];
    const float* y0 = (const float*)d_in[2];
    const float* aa = (const float*)d_in[3];
    const float* om = (const float*)d_in[4];
    const float* nz = (const float*)d_in[5];
    const float* gg = (const float*)d_in[6];
    float* out = (float*)d_out;

    unsigned long long* pub = (unsigned long long*)d_ws;
    int* flags = (int*)(pub + 2 * NPAD);

    hipLaunchKernelGGL(hopf_init_ws, dim3(2), dim3(512), 0, stream, pub, flags);
    hipLaunchKernelGGL(hopf_main, dim3(NBLK), dim3(TPB), 0, stream,
                       sc, x0, y0, aa, om, nz, gg, out, pub, flags);
}

// Round 2
// 59575.818 us; speedup vs baseline: 1.6318x; 1.6318x over previous
//
#include <hip/hip_runtime.h>

#define NN    500
#define TT    20000
#define NPAD  512
#define NBLK  8
#define NROW  64        // padded rows per block
#define TPB   512
#define RPT   4         // rows per thread
#define CPT   16        // cols per thread (strided by 32)
#define DTC   0.05f
#define SQDTC 0.22360679774997896f

// ---------------------------------------------------------------------------
// Coherence-point (Infinity Cache) accessors: sc0 sc1 = system-coherent,
// bypass L1/L2. No buffer_inv / buffer_wbl2 needed anywhere.
// ---------------------------------------------------------------------------
__device__ __forceinline__ void store_coh_u64(unsigned long long* p, unsigned long long v) {
    asm volatile("global_store_dwordx2 %0, %1, off sc0 sc1" :: "v"(p), "v"(v) : "memory");
}
__device__ __forceinline__ unsigned long long load_coh_u64(const unsigned long long* p) {
    unsigned long long v;
    asm volatile("global_load_dwordx2 %0, %1, off sc0 sc1\n\t"
                 "s_waitcnt vmcnt(0)" : "=v"(v) : "v"(p) : "memory");
    return v;
}
__device__ __forceinline__ void store_coh_u32(int* p, int v) {
    asm volatile("global_store_dword %0, %1, off sc0 sc1" :: "v"(p), "v"(v) : "memory");
}
__device__ __forceinline__ int load_coh_u32(const int* p) {
    int v;
    asm volatile("global_load_dword %0, %1, off sc0 sc1\n\t"
                 "s_waitcnt vmcnt(0)" : "=v"(v) : "v"(p) : "memory");
    return v;
}

__global__ __launch_bounds__(512) void hopf_init_ws(unsigned long long* pub, int* flags) {
    int i = blockIdx.x * blockDim.x + threadIdx.x;
    if (i < 2 * NPAD) pub[i] = 0ull;
    if (i < NBLK) flags[i] = 0;
}

__global__ __launch_bounds__(TPB) void hopf_main(
    const float* __restrict__ sc, const float* __restrict__ x0,
    const float* __restrict__ y0, const float* __restrict__ aa,
    const float* __restrict__ om, const float* __restrict__ noise,
    const float* __restrict__ gg, float* __restrict__ out,
    unsigned long long* __restrict__ pub, int* __restrict__ flags)
{
    const int tid  = threadIdx.x;
    const int blk  = blockIdx.x;
    const int cgrp = tid & 31;       // 32 column groups
    const int rgrp = tid >> 5;       // 16 row groups of RPT rows
    const int r0   = blk * NROW + rgrp * RPT;   // padded global row base

    __shared__ __align__(16) float2 xy[NPAD];   // full padded state (x,y)

    // ---- sc slice -> registers.  col(c) = cgrp + 32*c ----
    float scr[RPT][CPT];
#pragma unroll
    for (int r = 0; r < RPT; ++r) {
        int row = r0 + r;
#pragma unroll
        for (int c = 0; c < CPT; ++c) {
            int col = cgrp + 32 * c;
            scr[r][c] = (row < NN && col < NN) ? sc[row * NN + col] : 0.0f;
        }
    }

    // ---- deg per row (before pinning; same numeric order as before) ----
    float dsum[RPT];
#pragma unroll
    for (int r = 0; r < RPT; ++r) {
        float s = 0.f;
#pragma unroll
        for (int c = 0; c < CPT; ++c) s += scr[r][c];
        dsum[r] = s;
    }
#pragma unroll
    for (int m = 16; m >= 1; m >>= 1) {
#pragma unroll
        for (int r = 0; r < RPT; ++r) dsum[r] += __shfl_xor(dsum[r], m, 32);
    }

    // ---- pin the sc slice into VGPRs: opaque to the optimizer, so it
    // cannot demote/rematerialize the loads inside the t-loop ----
#pragma unroll
    for (int r = 0; r < RPT; ++r)
#pragma unroll
        for (int c = 0; c < CPT; ++c)
            asm volatile("" : "+v"(scr[r][c]));

    // ---- per-finalize-lane constants (lanes cgrp<RPT own row r0+cgrp) ----
    float a_i = 0.f, om_i = 0.f, deg_i = 0.f;
    int myrow = -1;
    if (cgrp < RPT) {
        int row = r0 + cgrp;
        deg_i = (cgrp == 0) ? dsum[0] : (cgrp == 1) ? dsum[1]
              : (cgrp == 2) ? dsum[2] : dsum[3];
        if (row < NN) { myrow = row; a_i = aa[row]; om_i = om[row]; }
    }
    const float g = gg[0];

    // ---- initial state into LDS ----
    xy[tid] = (tid < NN) ? make_float2(x0[tid], y0[tid]) : make_float2(0.f, 0.f);
    __syncthreads();

    // prefetched noise for step 0
    float2 nz = make_float2(0.f, 0.f);
    if (myrow >= 0) nz = *(const float2*)(noise + 2 * (size_t)myrow);

    for (int t = 0; t < TT; ++t) {
        // prefetch next step's noise (hidden under the matvec)
        float2 nz_next = make_float2(0.f, 0.f);
        if (myrow >= 0 && t + 1 < TT)
            nz_next = *(const float2*)(noise + (size_t)(t + 1) * (2 * NN) + 2 * (size_t)myrow);

        // ---- partial matvec: 4 rows x 16 strided cols per thread ----
        float2 acc[RPT];
#pragma unroll
        for (int r = 0; r < RPT; ++r) acc[r] = make_float2(0.f, 0.f);
#pragma unroll
        for (int c = 0; c < CPT; ++c) {
            float2 w = xy[cgrp + 32 * c];
#pragma unroll
            for (int r = 0; r < RPT; ++r) {
                acc[r].x += scr[r][c] * w.x;
                acc[r].y += scr[r][c] * w.y;
            }
        }
        // ---- reduce across the 32 column-group lanes ----
#pragma unroll
        for (int m = 16; m >= 1; m >>= 1) {
#pragma unroll
            for (int r = 0; r < RPT; ++r) {
                acc[r].x += __shfl_xor(acc[r].x, m, 32);
                acc[r].y += __shfl_xor(acc[r].y, m, 32);
            }
        }

        // ---- finalize + publish (lanes cgrp<RPT, real rows only) ----
        if (myrow >= 0) {
            float sx = (cgrp == 0) ? acc[0].x : (cgrp == 1) ? acc[1].x
                     : (cgrp == 2) ? acc[2].x : acc[3].x;
            float sy = (cgrp == 0) ? acc[0].y : (cgrp == 1) ? acc[1].y
                     : (cgrp == 2) ? acc[2].y : acc[3].y;
            float2 cur = xy[myrow];
            float r2 = cur.x * cur.x + cur.y * cur.y;
            float cx = sx - deg_i * cur.x;
            float cy = sy - deg_i * cur.y;
            float dx = (a_i - r2) * cur.x - om_i * cur.y + g * cx;
            float dy = (a_i - r2) * cur.y + om_i * cur.x + g * cy;
            float xn = cur.x + DTC * dx + SQDTC * nz.x;
            float yn = cur.y + DTC * dy + SQDTC * nz.y;
            out[(size_t)t * NN + myrow] = xn;
            float2 p = make_float2(xn, yn);
            unsigned long long pv;
            __builtin_memcpy(&pv, &p, 8);
            store_coh_u64(&pub[(size_t)(t & 1) * NPAD + myrow], pv);
        }
        nz = nz_next;

        if (t == TT - 1) break;   // uniform across grid

        // ---- order pub stores before flag: wait own stores acked at the
        // coherence point, barrier, then one flag store (no cache flushes) ----
        asm volatile("s_waitcnt vmcnt(0)" ::: "memory");
        __syncthreads();
        if (tid == 0) store_coh_u32(&flags[blk], t + 1);

        // ---- wait for all producers of step t ----
        if (tid < NBLK && tid != blk) {
            const int* fp = &flags[tid];
            while (load_coh_u32(fp) < t + 1) { }
        }
        __syncthreads();

        // ---- gather full state t+1: one coherent 8B load per thread ----
        unsigned long long pv = load_coh_u64(&pub[(size_t)(t & 1) * NPAD + tid]);
        float2 w;
        __builtin_memcpy(&w, &pv, 8);
        xy[tid] = w;
        __syncthreads();
    }
}

extern "C" void kernel_launch(void* const* d_in, const int* in_sizes, int n_in,
                              void* d_out, int out_size, void* d_ws, size_t ws_size,
                              hipStream_t stream) {
    const float* sc = (const float*)d_in[0];
    const float* x0 = (const float*)d_in[1];
    const float* y0 = (const float*)d_in[2];
    const float* aa = (const float*)d_in[3];
    const float* om = (const float*)d_in[4];
    const float* nz = (const float*)d_in[5];
    const float* gg = (const float*)d_in[6];
    float* out = (float*)d_out;

    unsigned long long* pub = (unsigned long long*)d_ws;
    int* flags = (int*)(pub + 2 * NPAD);

    hipLaunchKernelGGL(hopf_init_ws, dim3(2), dim3(512), 0, stream, pub, flags);
    hipLaunchKernelGGL(hopf_main, dim3(NBLK), dim3(TPB), 0, stream,
                       sc, x0, y0, aa, om, nz, gg, out, pub, flags);
}

// Round 5
// 42637.473 us; speedup vs baseline: 2.2801x; 1.3973x over previous
//
#include <hip/hip_runtime.h>

#define NN    500
#define TT    20000
#define NPAD  512
#define NBLK  8
#define NROW  64        // padded rows per block
#define TPB   512
#define RPT   4         // rows per thread
#define CPT   16        // cols per thread (strided by 32)
#define DTC   0.05f
#define SQDTC 0.22360679774997896f

typedef unsigned int u32x4 __attribute__((ext_vector_type(4)));

// ---------------------------------------------------------------------------
// Fully-coherent 16B accessors (sc0 sc1): single-instruction load/store, no
// cache-maintenance ops. Packet layout (x, tag, y, tag): each 8B half carries
// one data word + one tag copy, so "both tags fresh" => both halves landed.
// ---------------------------------------------------------------------------
__device__ __forceinline__ void store_coh_u128(u32x4* p, u32x4 v) {
    asm volatile("global_store_dwordx4 %0, %1, off sc0 sc1" :: "v"(p), "v"(v) : "memory");
}
__device__ __forceinline__ u32x4 load_coh_u128(const u32x4* p) {
    u32x4 v;
    asm volatile("global_load_dwordx4 %0, %1, off sc0 sc1\n\t"
                 "s_waitcnt vmcnt(0)" : "=v"(v) : "v"(p) : "memory");
    return v;
}

// ws layout: pub[2][NPAD] of u32x4 = 16 KB
__global__ __launch_bounds__(512) void hopf_init_ws(u32x4* pub) {
    int i = blockIdx.x * blockDim.x + threadIdx.x;
    if (i < 2 * NPAD) pub[i] = (u32x4){0u, 0u, 0u, 0u};
}

__global__ __launch_bounds__(TPB) void hopf_main(
    const float* __restrict__ sc, const float* __restrict__ x0,
    const float* __restrict__ y0, const float* __restrict__ aa,
    const float* __restrict__ om, const float* __restrict__ noise,
    const float* __restrict__ gg, float* __restrict__ out,
    u32x4* __restrict__ pub)
{
    const int tid  = threadIdx.x;
    const int blk  = blockIdx.x;
    const int cgrp = tid & 31;       // 32 column groups
    const int rgrp = tid >> 5;       // 16 row groups of RPT rows
    const int r0   = blk * NROW + rgrp * RPT;   // padded global row base

    __shared__ __align__(16) float2 xy[NPAD];   // full padded state (x,y)

    // ---- sc slice -> registers.  col(c) = cgrp + 32*c ----
    float scr[RPT][CPT];
#pragma unroll
    for (int r = 0; r < RPT; ++r) {
        int row = r0 + r;
#pragma unroll
        for (int c = 0; c < CPT; ++c) {
            int col = cgrp + 32 * c;
            scr[r][c] = (row < NN && col < NN) ? sc[row * NN + col] : 0.0f;
        }
    }

    // ---- deg per row ----
    float dsum[RPT];
#pragma unroll
    for (int r = 0; r < RPT; ++r) {
        float s = 0.f;
#pragma unroll
        for (int c = 0; c < CPT; ++c) s += scr[r][c];
        dsum[r] = s;
    }
#pragma unroll
    for (int m = 16; m >= 1; m >>= 1) {
#pragma unroll
        for (int r = 0; r < RPT; ++r) dsum[r] += __shfl_xor(dsum[r], m, 32);
    }

    // ---- pin the sc slice (optimizer cannot demote/rematerialize) ----
#pragma unroll
    for (int r = 0; r < RPT; ++r)
#pragma unroll
        for (int c = 0; c < CPT; ++c)
            asm volatile("" : "+v"(scr[r][c]));

    // ---- per-finalize-lane constants (lanes cgrp<RPT own row r0+cgrp) ----
    float a_i = 0.f, om_i = 0.f, deg_i = 0.f;
    int myrow = -1;
    if (cgrp < RPT) {
        int row = r0 + cgrp;
        deg_i = (cgrp == 0) ? dsum[0] : (cgrp == 1) ? dsum[1]
              : (cgrp == 2) ? dsum[2] : dsum[3];
        if (row < NN) { myrow = row; a_i = aa[row]; om_i = om[row]; }
    }
    const float g = gg[0];

    // ---- initial state into LDS (padding rows stay zero forever) ----
    xy[tid] = (tid < NN) ? make_float2(x0[tid], y0[tid]) : make_float2(0.f, 0.f);
    __syncthreads();

    // prefetched noise for step 0
    float2 nz = make_float2(0.f, 0.f);
    if (myrow >= 0) nz = *(const float2*)(noise + 2 * (size_t)myrow);

    for (int t = 0; t < TT; ++t) {
        // prefetch next step's noise (hidden under the matvec)
        float2 nz_next = make_float2(0.f, 0.f);
        if (myrow >= 0 && t + 1 < TT)
            nz_next = *(const float2*)(noise + (size_t)(t + 1) * (2 * NN) + 2 * (size_t)myrow);

        // ---- partial matvec: 4 rows x 16 strided cols per thread ----
        float2 acc[RPT];
#pragma unroll
        for (int r = 0; r < RPT; ++r) acc[r] = make_float2(0.f, 0.f);
#pragma unroll
        for (int c = 0; c < CPT; ++c) {
            float2 w = xy[cgrp + 32 * c];
#pragma unroll
            for (int r = 0; r < RPT; ++r) {
                acc[r].x += scr[r][c] * w.x;
                acc[r].y += scr[r][c] * w.y;
            }
        }
        // ---- reduce across the 32 column-group lanes ----
#pragma unroll
        for (int m = 16; m >= 1; m >>= 1) {
#pragma unroll
            for (int r = 0; r < RPT; ++r) {
                acc[r].x += __shfl_xor(acc[r].x, m, 32);
                acc[r].y += __shfl_xor(acc[r].y, m, 32);
            }
        }

        // ---- finalize + publish tagged 16B packet (lanes cgrp<RPT) ----
        if (myrow >= 0) {
            float sx = (cgrp == 0) ? acc[0].x : (cgrp == 1) ? acc[1].x
                     : (cgrp == 2) ? acc[2].x : acc[3].x;
            float sy = (cgrp == 0) ? acc[0].y : (cgrp == 1) ? acc[1].y
                     : (cgrp == 2) ? acc[2].y : acc[3].y;
            float2 cur = xy[myrow];
            float r2 = cur.x * cur.x + cur.y * cur.y;
            float cx = sx - deg_i * cur.x;
            float cy = sy - deg_i * cur.y;
            float dx = (a_i - r2) * cur.x - om_i * cur.y + g * cx;
            float dy = (a_i - r2) * cur.y + om_i * cur.x + g * cy;
            float xn = cur.x + DTC * dx + SQDTC * nz.x;
            float yn = cur.y + DTC * dy + SQDTC * nz.y;
            out[(size_t)t * NN + myrow] = xn;
            u32x4 pkt = { __float_as_uint(xn), (unsigned)(t + 1),
                          __float_as_uint(yn), (unsigned)(t + 1) };
            store_coh_u128(&pub[(size_t)(t & 1) * NPAD + myrow], pkt);
        }
        nz = nz_next;

        if (t == TT - 1) break;   // uniform across grid

        // protect xy: all matvec/finalize reads of xy done before overwrite
        __syncthreads();

        // ---- gather: poll own tagged slot until step t+1 visible.
        //      ONLY real rows — padding rows are never published! ----
        if (tid < NN) {
            const u32x4* slot = &pub[(size_t)(t & 1) * NPAD + tid];
            u32x4 v;
            do {
                v = load_coh_u128(slot);
            } while ((int)v.y < t + 1 || (int)v.w < t + 1);
            xy[tid] = make_float2(__uint_as_float(v.x), __uint_as_float(v.z));
        }
        __syncthreads();
    }
}

extern "C" void kernel_launch(void* const* d_in, const int* in_sizes, int n_in,
                              void* d_out, int out_size, void* d_ws, size_t ws_size,
                              hipStream_t stream) {
    const float* sc = (const float*)d_in[0];
    const float* x0 = (const float*)d_in[1];
    const float* y0 = (const float*)d_in[2];
    const float* aa = (const float*)d_in[3];
    const float* om = (const float*)d_in[4];
    const float* nz = (const float*)d_in[5];
    const float* gg = (const float*)d_in[6];
    float* out = (float*)d_out;

    u32x4* pub = (u32x4*)d_ws;   // 2*NPAD*16 = 16 KB

    hipLaunchKernelGGL(hopf_init_ws, dim3(2), dim3(512), 0, stream, pub);
    hipLaunchKernelGGL(hopf_main, dim3(NBLK), dim3(TPB), 0, stream,
                       sc, x0, y0, aa, om, nz, gg, out, pub);
}